// Round 2
// baseline (144.894 us; speedup 1.0000x reference)
//
#include <hip/hip_runtime.h>
#include <hip/hip_bf16.h>

// CoincidenceDetector: S[b,n] = sum_d |w_d| * [|q[b,d]-pt[n,d]|<5] * exp(-|dt|/3)
// pt = 20 - 15*sigmoid(patterns)
//
// exp(-|dt|/3) = min(Eq*Ip, Iq*Ep), Eq=e^{q/3}, Ep=e^{pt/3}. Window |dt|<5
// <=> k > |w|*e^{-5/3} (strict, by monotonicity). 6 full-rate VALU ops/element,
// zero transcendentals in the hot loop.
//
// R2 changes vs R1 (83us, VALUBusy 50%, occ 8 waves/CU):
//  - readfirstlane(wave id) so Eq/Iq loads scalarize to s_load_dwordx8
//    (R1 emitted divergent per-lane loads of wave-uniform data -> 2x VALU)
//  - d split into 4 quarters -> grid 1024, LDS 32KB/block, 4 blocks/CU target
//  - partial sums to ws + tiny reduce kernel (atomic fallback if ws too small)

static constexpr float kC2    = 0.48089834696298783f;   // 1/(3*ln2)
static constexpr float kTheta = 0.18887560283756183f;   // exp(-5/3)

#define B_      64
#define N_      16384
#define D_      256
#define NTILE   64
#define DQ      64            // d per block (quarter)
#define THREADS 512           // 8 waves
#define BPW     8             // batches per wave

__global__ void cd_pre(const float* __restrict__ q, const float* __restrict__ w,
                       float* __restrict__ Eq, float* __restrict__ Iq,
                       float* __restrict__ tw) {
    int e = blockIdx.x * 256 + threadIdx.x;
    if (e < B_ * D_) {
        float qv = q[e];
        Eq[e] = exp2f(qv * kC2);
        Iq[e] = exp2f(-qv * kC2);
    }
    if (e < D_) tw[e] = kTheta * fabsf(w[e]);
}

template<int ATOMIC>
__global__ __launch_bounds__(THREADS, 8) void cd_main(
        const float* __restrict__ patterns,
        const float* __restrict__ weights,
        const float* __restrict__ Eq,
        const float* __restrict__ Iq,
        const float* __restrict__ tw,
        float* __restrict__ outp) {
    // quad-granule XOR swizzle: float4 at (row, cq) lives at cq^(row&15)
    // -> ds_read_b128 start banks spread over 8 positions
    __shared__ float sEp[NTILE * DQ];   // 16 KB
    __shared__ float sIp[NTILE * DQ];   // 16 KB

    const int t    = threadIdx.x;
    const int tile = blockIdx.x >> 2;
    const int quar = blockIdx.x & 3;
    const int n0   = tile * NTILE;
    const int d0   = quar * DQ;

    // ---- stage 64n x 64d tile (each element computed exactly once globally)
#pragma unroll
    for (int it = 0; it < 2; ++it) {
        int e4  = it * THREADS + t;     // float4 id 0..1023
        int row = e4 >> 4;              // 0..63
        int cq  = e4 & 15;              // quad col 0..15
        float4 x  = *(const float4*)&patterns[(size_t)(n0 + row) * D_ + d0 + cq * 4];
        float4 wv = *(const float4*)&weights[d0 + cq * 4];
        float xs[4] = {x.x, x.y, x.z, x.w};
        float ws4[4] = {wv.x, wv.y, wv.z, wv.w};
        float ef[4], if_[4];
#pragma unroll
        for (int j = 0; j < 4; ++j) {
            float sg = 1.0f / (1.0f + __expf(-xs[j]));
            float pt = fmaf(-15.0f, sg, 20.0f);
            float wa = fabsf(ws4[j]);
            float u  = pt * kC2;
            ef[j]  = wa * exp2f(u);
            if_[j] = wa * exp2f(-u);
        }
        int idx = row * DQ + ((cq ^ (row & 15)) << 2);
        *(float4*)&sEp[idx] = make_float4(ef[0], ef[1], ef[2], ef[3]);
        *(float4*)&sIp[idx] = make_float4(if_[0], if_[1], if_[2], if_[3]);
    }
    __syncthreads();

    const int l   = t & 63;
    const int uwv = __builtin_amdgcn_readfirstlane(t >> 6);  // uniform wave id

    float acc[BPW];
#pragma unroll
    for (int i = 0; i < BPW; ++i) acc[i] = 0.f;

    const int m = l & 15;
#pragma unroll 2
    for (int c = 0; c < DQ / 8; ++c) {              // 8 chunks of 8 d
        int qa = l * DQ + (((2 * c)     ^ m) << 2);
        int qb = l * DQ + (((2 * c + 1) ^ m) << 2);
        float4 e0 = *(const float4*)&sEp[qa];
        float4 e1 = *(const float4*)&sEp[qb];
        float4 i0 = *(const float4*)&sIp[qa];
        float4 i1 = *(const float4*)&sIp[qb];
        float epv[8] = {e0.x, e0.y, e0.z, e0.w, e1.x, e1.y, e1.z, e1.w};
        float ipv[8] = {i0.x, i0.y, i0.z, i0.w, i1.x, i1.y, i1.z, i1.w};
        const float* twc = tw + d0 + c * 8;          // uniform -> s_load
#pragma unroll
        for (int bi = 0; bi < BPW; ++bi) {
            int b = uwv * BPW + bi;                  // uniform
            const float* eqp = Eq + (size_t)b * D_ + d0 + c * 8;  // s_load
            const float* iqp = Iq + (size_t)b * D_ + d0 + c * 8;  // s_load
#pragma unroll
            for (int dd = 0; dd < 8; ++dd) {
                float a  = eqp[dd] * ipv[dd];
                float bb = iqp[dd] * epv[dd];
                float k  = fminf(a, bb);
                acc[bi] += (k > twc[dd]) ? k : 0.f;
            }
        }
    }

#pragma unroll
    for (int bi = 0; bi < BPW; ++bi) {
        int b = uwv * BPW + bi;
        if (ATOMIC) {
            atomicAdd(&outp[(size_t)b * N_ + n0 + l], acc[bi]);
        } else {
            // partials: [quar][b][n]
            outp[((size_t)quar * B_ + b) * N_ + n0 + l] = acc[bi];
        }
    }
}

__global__ void cd_reduce(const float4* __restrict__ part, float4* __restrict__ S) {
    const int PQ = B_ * N_ / 4;                      // float4s per quarter
    int i = blockIdx.x * 256 + threadIdx.x;          // 0 .. PQ-1
    float4 a = part[i];
    float4 b = part[i + PQ];
    float4 c = part[i + 2 * PQ];
    float4 d = part[i + 3 * PQ];
    float4 r;
    r.x = (a.x + b.x) + (c.x + d.x);
    r.y = (a.y + b.y) + (c.y + d.y);
    r.z = (a.z + b.z) + (c.z + d.z);
    r.w = (a.w + b.w) + (c.w + d.w);
    S[i] = r;
}

extern "C" void kernel_launch(void* const* d_in, const int* in_sizes, int n_in,
                              void* d_out, int out_size, void* d_ws, size_t ws_size,
                              hipStream_t stream) {
    const float* q        = (const float*)d_in[0];
    const float* patterns = (const float*)d_in[1];
    const float* weights  = (const float*)d_in[2];
    float* S = (float*)d_out;

    float* Eq = (float*)d_ws;               // 64KB
    float* Iq = Eq + B_ * D_;               // 64KB
    float* tw = Iq + B_ * D_;               // 1KB
    float* part = tw + D_;                  // 4 * B * N floats = 16 MB
    const size_t need = (size_t)(2 * B_ * D_ + D_) * 4 + (size_t)4 * B_ * N_ * 4;

    cd_pre<<<(B_ * D_ + 255) / 256, 256, 0, stream>>>(q, weights, Eq, Iq, tw);

    const int grid_main = (N_ / NTILE) * 4;  // 1024
    if (ws_size >= need) {
        cd_main<0><<<grid_main, THREADS, 0, stream>>>(patterns, weights, Eq, Iq, tw, part);
        cd_reduce<<<(B_ * N_ / 4) / 256, 256, 0, stream>>>((const float4*)part, (float4*)S);
    } else {
        hipMemsetAsync(d_out, 0, (size_t)out_size * sizeof(float), stream);
        cd_main<1><<<grid_main, THREADS, 0, stream>>>(patterns, weights, Eq, Iq, tw, S);
    }
}